// Round 1
// baseline (1915.773 us; speedup 1.0000x reference)
//
#include <hip/hip_runtime.h>
#include <hip/hip_bf16.h>
#include <math.h>

#define HH 96
#define WWID 96
#define HW 9216
#define CC 256
#define BB 2

// in_w [C][C] -> wT [k][c]
__global__ void k_transpose_w(const float* __restrict__ in_w, float* __restrict__ wT) {
  int k = blockIdx.x, c = threadIdx.x;
  wT[k * CC + c] = in_w[c * CC + k];
}

// pack 6 conv3x3 weight tensors into Wall[(ci*9+j)*648+co], bias Ball[648]
__global__ void k_packw(const float* __restrict__ ow1, const float* __restrict__ ob1,
                        const float* __restrict__ mw1, const float* __restrict__ mb1,
                        const float* __restrict__ ow2, const float* __restrict__ ob2,
                        const float* __restrict__ mw2, const float* __restrict__ mb2,
                        const float* __restrict__ ow4, const float* __restrict__ ob4,
                        const float* __restrict__ mw4, const float* __restrict__ mb4,
                        float* __restrict__ Wall, float* __restrict__ Ball) {
  int idx = blockIdx.x * 256 + threadIdx.x;
  if (idx >= 648 * 2304) return;
  int co = idx % 648;
  int rest = idx / 648;
  int j = rest % 9, ci = rest / 9;
  int d = co / 216, c2 = co - d * 216;
  const float* ow = d == 0 ? ow1 : (d == 1 ? ow2 : ow4);
  const float* mw = d == 0 ? mw1 : (d == 1 ? mw2 : mw4);
  float v = (c2 < 144) ? ow[c2 * 2304 + ci * 9 + j] : mw[(c2 - 144) * 2304 + ci * 9 + j];
  Wall[idx] = v;
  if (idx < 648) {
    const float* obv = d == 0 ? ob1 : (d == 1 ? ob2 : ob4);
    const float* mbv = d == 0 ? mb1 : (d == 1 ? mb2 : mb4);
    Ball[idx] = (c2 < 144) ? obv[c2] : mbv[c2 - 144];
  }
}

// conv1x1 + LayerNorm over channels for the query. Output NHWC q_hwc[b][hw][c].
// block = 256 thr = 4 waves; each wave handles 8 pixels; block covers 32 consecutive hw.
__global__ void k_conv1_ln_q(const float* __restrict__ qin, const float* __restrict__ wT,
                             const float* __restrict__ in_b, const float* __restrict__ ln_g,
                             const float* __restrict__ ln_b, float* __restrict__ q_hwc) {
  int bx = blockIdx.x;
  int b = bx / 288;
  int hw0 = (bx % 288) * 32;
  int t = threadIdx.x;
  int lane = t & 63;
  int wv_id = t >> 6;
  __shared__ float xs[32 * 257];
  const float* qb = qin + (size_t)b * CC * HW;
  #pragma unroll
  for (int i = 0; i < 32; ++i) {
    int idx = t + i * 256;
    int p = idx & 31;
    int k = idx >> 5;
    xs[p * 257 + k] = qb[k * HW + hw0 + p];
  }
  __syncthreads();
  float acc[8][4];
  #pragma unroll
  for (int p = 0; p < 8; ++p) { acc[p][0]=0.f; acc[p][1]=0.f; acc[p][2]=0.f; acc[p][3]=0.f; }
  const float4* wT4 = (const float4*)wT;
  int p0 = wv_id * 8;
  for (int k = 0; k < 256; ++k) {
    float4 wv = wT4[k * 64 + lane];
    #pragma unroll
    for (int p = 0; p < 8; ++p) {
      float xv = xs[(p0 + p) * 257 + k];
      acc[p][0] += wv.x * xv; acc[p][1] += wv.y * xv;
      acc[p][2] += wv.z * xv; acc[p][3] += wv.w * xv;
    }
  }
  float4 bb = ((const float4*)in_b)[lane];
  float4 g4 = ((const float4*)ln_g)[lane];
  float4 b4 = ((const float4*)ln_b)[lane];
  #pragma unroll
  for (int p = 0; p < 8; ++p) {
    float y0 = acc[p][0] + bb.x, y1 = acc[p][1] + bb.y;
    float y2 = acc[p][2] + bb.z, y3 = acc[p][3] + bb.w;
    float s1 = y0 + y1 + y2 + y3;
    float s2 = y0*y0 + y1*y1 + y2*y2 + y3*y3;
    #pragma unroll
    for (int off = 32; off; off >>= 1) { s1 += __shfl_xor(s1, off); s2 += __shfl_xor(s2, off); }
    float mu = s1 * (1.f / 256.f);
    float rstd = rsqrtf(s2 * (1.f / 256.f) - mu * mu + 1e-5f);
    float4 o;
    o.x = (y0 - mu) * rstd * g4.x + b4.x;
    o.y = (y1 - mu) * rstd * g4.y + b4.y;
    o.z = (y2 - mu) * rstd * g4.z + b4.z;
    o.w = (y3 - mu) * rstd * g4.w + b4.w;
    ((float4*)q_hwc)[((size_t)b * HW + hw0 + p0 + p) * 64 + lane] = o;
  }
}

// NHWC -> NCHW transpose (per batch)
__global__ void k_tr(const float* __restrict__ q_hwc, float* __restrict__ q_chw) {
  __shared__ float tile[32][33];
  int hw0 = blockIdx.x * 32, c0 = blockIdx.y * 32, b = blockIdx.z;
  int tx = threadIdx.x, ty = threadIdx.y;
  const float* in = q_hwc + (size_t)b * HW * CC;
  float* out = q_chw + (size_t)b * CC * HW;
  #pragma unroll
  for (int i = 0; i < 4; ++i) {
    int r = ty + i * 8;
    tile[r][tx] = in[(size_t)(hw0 + r) * CC + c0 + tx];
  }
  __syncthreads();
  #pragma unroll
  for (int i = 0; i < 4; ++i) {
    int r = ty + i * 8;
    out[(size_t)(c0 + r) * HW + hw0 + tx] = tile[tx][r];
  }
}

// supports: conv1x1 + LN per (b,e) image of 9 positions; also pooled max.
__global__ void k_conv1_ln_s(const float* __restrict__ sup, const float* __restrict__ wT,
                             const float* __restrict__ in_b, const float* __restrict__ ln_g,
                             const float* __restrict__ ln_b, float* __restrict__ s_ln,
                             float* __restrict__ pooled) {
  int img = blockIdx.x;  // b*3+e
  int t = threadIdx.x;
  __shared__ float xs[2304];
  __shared__ float red1[256], red2[256];
  #pragma unroll
  for (int p = 0; p < 9; ++p) xs[t * 9 + p] = sup[(size_t)img * 2304 + t * 9 + p];
  __syncthreads();
  float acc[9];
  #pragma unroll
  for (int p = 0; p < 9; ++p) acc[p] = 0.f;
  for (int k = 0; k < 256; ++k) {
    float wv = wT[k * CC + t];
    #pragma unroll
    for (int p = 0; p < 9; ++p) acc[p] += wv * xs[k * 9 + p];
  }
  float bias = in_b[t];
  #pragma unroll
  for (int p = 0; p < 9; ++p) acc[p] += bias;
  float g = ln_g[t], be = ln_b[t];
  float vals[9];
  #pragma unroll
  for (int p = 0; p < 9; ++p) {
    red1[t] = acc[p]; red2[t] = acc[p] * acc[p];
    __syncthreads();
    for (int s = 128; s > 0; s >>= 1) {
      if (t < s) { red1[t] += red1[t + s]; red2[t] += red2[t + s]; }
      __syncthreads();
    }
    float mu = red1[0] * (1.f / 256.f);
    float var = red2[0] * (1.f / 256.f) - mu * mu;
    float rstd = rsqrtf(var + 1e-5f);
    vals[p] = (acc[p] - mu) * rstd * g + be;
    __syncthreads();
  }
  #pragma unroll
  for (int p = 0; p < 9; ++p) s_ln[(size_t)img * 2304 + t * 9 + p] = vals[p];
  float mx = vals[0];
  #pragma unroll
  for (int p = 1; p < 9; ++p) mx = fmaxf(mx, vals[p]);
  int b = img / 3, e = img % 3;
  pooled[((size_t)b * 6 + e * 2 + (t >> 7)) * 128 + (t & 127)] = mx;
}

// big 3x3 conv: q_chw [B][256][96][96] -> 648 output channels (offsets + mask logits)
// block: 64 out-channels x one output row (96 px); thread: co=t&63, px-chunk=(t>>6)*24
__global__ void __launch_bounds__(256) k_conv3(const float* __restrict__ q,
                        const float* __restrict__ Wall, const float* __restrict__ Ball,
                        float* __restrict__ offbuf, float* __restrict__ mskbuf) {
  int h = blockIdx.x;
  int co = blockIdx.y * 64 + (threadIdx.x & 63);
  int chunk = threadIdx.x >> 6;
  int b = blockIdx.z;
  __shared__ float xr[4][3][100];
  float acc[24];
  #pragma unroll
  for (int p = 0; p < 24; ++p) acc[p] = 0.f;
  const float* qb = q + (size_t)b * CC * HW;
  bool active = co < 648;
  for (int ci0 = 0; ci0 < 256; ci0 += 4) {
    __syncthreads();
    for (int i = threadIdx.x; i < 1152; i += 256) {
      int cio = i / 288;
      int r = (i % 288) / 96;
      int col = i % 96;
      int hhh = h + r - 1;
      xr[cio][r][col + 1] = (hhh >= 0 && hhh < HH) ? qb[(size_t)(ci0 + cio) * HW + hhh * WWID + col] : 0.f;
      if (col == 0) { xr[cio][r][0] = 0.f; xr[cio][r][97] = 0.f; }
    }
    __syncthreads();
    if (active) {
      #pragma unroll
      for (int cio = 0; cio < 4; ++cio) {
        float w9[9];
        #pragma unroll
        for (int j = 0; j < 9; ++j) w9[j] = Wall[(size_t)((ci0 + cio) * 9 + j) * 648 + co];
        int base = chunk * 24;
        #pragma unroll
        for (int r = 0; r < 3; ++r) {
          float xv[28];
          const float4* xp = (const float4*)&xr[cio][r][base];
          #pragma unroll
          for (int i4 = 0; i4 < 7; ++i4) {
            float4 v = xp[i4];
            xv[i4 * 4 + 0] = v.x; xv[i4 * 4 + 1] = v.y;
            xv[i4 * 4 + 2] = v.z; xv[i4 * 4 + 3] = v.w;
          }
          #pragma unroll
          for (int dx = 0; dx < 3; ++dx) {
            float wvv = w9[r * 3 + dx];
            #pragma unroll
            for (int p = 0; p < 24; ++p) acc[p] += wvv * xv[p + dx];
          }
        }
      }
    }
  }
  if (active) {
    int d = co / 216, c2 = co - d * 216;
    float bias = Ball[co];
    float* obase;
    if (c2 < 144) obase = offbuf + ((size_t)(d * BB + b) * 144 + c2) * HW + h * WWID;
    else          obase = mskbuf + ((size_t)(d * BB + b) * 72 + (c2 - 144)) * HW + h * WWID;
    int basep = chunk * 24;
    #pragma unroll
    for (int p = 0; p < 24; ++p) obase[basep + p] = acc[p] + bias;
  }
}

// softmax over 72 mask channels per pixel, in place
__global__ void k_softmax(float* __restrict__ msk) {
  int gid = blockIdx.x * 256 + threadIdx.x;
  int img = gid / HW, hw = gid % HW;
  float* p = msk + (size_t)img * 72 * HW + hw;
  float mx = -1e30f;
  for (int r = 0; r < 72; ++r) mx = fmaxf(mx, p[r * HW]);
  float s = 0.f;
  for (int r = 0; r < 72; ++r) s += __expf(p[r * HW] - mx);
  float rinv = 1.f / s;
  for (int r = 0; r < 72; ++r) p[r * HW] = __expf(p[r * HW] - mx) * rinv;
}

// sim0 branch: grouped 1x1 with pooled weights. block = 8 px x 32 lanes.
__global__ void k_sim0(const float* __restrict__ qt, const float* __restrict__ pooled,
                       float* __restrict__ sim) {
  int b = blockIdx.z, h = blockIdx.y, seg = blockIdx.x;
  int t = threadIdx.x;
  int pxl = t >> 5, lane = t & 31;
  int wcol = seg * 8 + pxl;
  int hw = h * WWID + wcol;
  __shared__ float plds[768];
  for (int i = t; i < 768; i += 256) plds[i] = pooled[(size_t)b * 768 + i];
  __syncthreads();
  const float* qtb = qt + (size_t)b * HW * CC;
  float acc[6] = {0.f, 0.f, 0.f, 0.f, 0.f, 0.f};
  #pragma unroll
  for (int m = 0; m < 8; ++m) {
    int cfull = m * 32 + lane;
    float qv = qtb[(size_t)hw * CC + cfull];
    if (m < 4) {
      int cp = cfull;
      acc[0] += plds[0 * 128 + cp] * qv;
      acc[1] += plds[1 * 128 + cp] * qv;
      acc[2] += plds[2 * 128 + cp] * qv;
    } else {
      int cp = cfull - 128;
      acc[3] += plds[3 * 128 + cp] * qv;
      acc[4] += plds[4 * 128 + cp] * qv;
      acc[5] += plds[5 * 128 + cp] * qv;
    }
  }
  #pragma unroll
  for (int r = 0; r < 6; ++r) {
    float v = acc[r];
    #pragma unroll
    for (int off = 16; off; off >>= 1) v += __shfl_down(v, off, 32);
    if (lane == 0) sim[((size_t)b * 24 + r) * HW + hw] = v;
  }
}

// deformable conv: block = 8 px x 32 lanes, one (b, dilation) per blockIdx.z
__global__ void k_deform(const float* __restrict__ qt, const float* __restrict__ offbuf,
                         const float* __restrict__ mskbuf, const float* __restrict__ s_ln,
                         float* __restrict__ sim) {
  int z = blockIdx.z;
  int d_idx = z >> 1, b = z & 1;
  int dil = 1 << d_idx;
  int h = blockIdx.y, seg = blockIdx.x;
  int t = threadIdx.x;
  int pxl = t >> 5, lane = t & 31;
  int wcol = seg * 8 + pxl;
  int hw = h * WWID + wcol;
  __shared__ float wlds[6912];
  for (int i = t; i < 6912; i += 256) wlds[i] = s_ln[(size_t)b * 6912 + i];
  __syncthreads();
  const float* ob = offbuf + (size_t)z * 144 * HW + hw;
  const float* mb = mskbuf + (size_t)z * 72 * HW + hw;
  const float* qtb = qt + (size_t)b * HW * CC;
  float acc[6] = {0.f, 0.f, 0.f, 0.f, 0.f, 0.f};
  for (int og = 0; og < 8; ++og) {
    int cfull = og * 32 + lane;
    #pragma unroll
    for (int k = 0; k < 9; ++k) {
      float dy = ob[((og * 9 + k) * 2 + 0) * HW];
      float dx = ob[((og * 9 + k) * 2 + 1) * HW];
      float mval = mb[(og * 9 + k) * HW];
      float py = (float)(h + (k / 3) * dil - dil) + dy;
      float px = (float)(wcol + (k % 3) * dil - dil) + dx;
      float y0f = floorf(py), x0f = floorf(px);
      int y0 = (int)y0f, x0 = (int)x0f;
      float wy = py - y0f, wx = px - x0f;
      float w00 = (1.f - wy) * (1.f - wx), w01 = (1.f - wy) * wx;
      float w10 = wy * (1.f - wx), w11 = wy * wx;
      float s = 0.f;
      if ((unsigned)y0 < 96u && (unsigned)x0 < 96u)
        s += w00 * qtb[(size_t)(y0 * 96 + x0) * CC + cfull];
      if ((unsigned)y0 < 96u && (unsigned)(x0 + 1) < 96u)
        s += w01 * qtb[(size_t)(y0 * 96 + x0 + 1) * CC + cfull];
      if ((unsigned)(y0 + 1) < 96u && (unsigned)x0 < 96u)
        s += w10 * qtb[(size_t)((y0 + 1) * 96 + x0) * CC + cfull];
      if ((unsigned)(y0 + 1) < 96u && (unsigned)(x0 + 1) < 96u)
        s += w11 * qtb[(size_t)((y0 + 1) * 96 + x0 + 1) * CC + cfull];
      s *= mval;
      if (og < 4) {
        int cp = cfull;
        acc[0] += wlds[(0 * 256 + 0 * 128 + cp) * 9 + k] * s;  // r=0: e=0,half=0
        acc[1] += wlds[(0 * 256 + 1 * 128 + cp) * 9 + k] * s;  // r=1: e=0,half=1
        acc[2] += wlds[(1 * 256 + 0 * 128 + cp) * 9 + k] * s;  // r=2: e=1,half=0
      } else {
        int cp = cfull - 128;
        acc[3] += wlds[(1 * 256 + 1 * 128 + cp) * 9 + k] * s;  // r=3: e=1,half=1
        acc[4] += wlds[(2 * 256 + 0 * 128 + cp) * 9 + k] * s;  // r=4: e=2,half=0
        acc[5] += wlds[(2 * 256 + 1 * 128 + cp) * 9 + k] * s;  // r=5: e=2,half=1
      }
    }
  }
  #pragma unroll
  for (int r = 0; r < 6; ++r) {
    float v = acc[r];
    #pragma unroll
    for (int off = 16; off; off >>= 1) v += __shfl_down(v, off, 32);
    if (lane == 0) sim[((size_t)b * 24 + 6 + 6 * d_idx + r) * HW + hw] = v;
  }
}

// out 1x1 conv: sim [B][24][HW] x out_w [256][24] -> out [B][256][HW]
__global__ void k_outconv(const float* __restrict__ sim, const float* __restrict__ out_w,
                          const float* __restrict__ out_b, float* __restrict__ out) {
  int hw = blockIdx.x * 256 + threadIdx.x;
  int co = blockIdx.y, b = blockIdx.z;
  const float* simb = sim + (size_t)b * 24 * HW;
  float a = out_b[co];
  #pragma unroll
  for (int r = 0; r < 24; ++r) a += out_w[co * 24 + r] * simb[(size_t)r * HW + hw];
  out[((size_t)b * CC + co) * HW + hw] = a;
}

extern "C" void kernel_launch(void* const* d_in, const int* in_sizes, int n_in,
                              void* d_out, int out_size, void* d_ws, size_t ws_size,
                              hipStream_t stream) {
  const float* querys = (const float*)d_in[0];
  const float* sup    = (const float*)d_in[1];
  const float* in_w   = (const float*)d_in[2];
  const float* in_b   = (const float*)d_in[3];
  const float* ln_g   = (const float*)d_in[4];
  const float* ln_b   = (const float*)d_in[5];
  const float* out_w  = (const float*)d_in[6];
  const float* out_b  = (const float*)d_in[7];
  const float* ow1 = (const float*)d_in[8];
  const float* ob1 = (const float*)d_in[9];
  const float* mw1 = (const float*)d_in[10];
  const float* mb1 = (const float*)d_in[11];
  const float* ow2 = (const float*)d_in[12];
  const float* ob2 = (const float*)d_in[13];
  const float* mw2 = (const float*)d_in[14];
  const float* mb2 = (const float*)d_in[15];
  const float* ow4 = (const float*)d_in[16];
  const float* ob4 = (const float*)d_in[17];
  const float* mw4 = (const float*)d_in[18];
  const float* mb4 = (const float*)d_in[19];
  float* out = (float*)d_out;

  float* ws_f   = (float*)d_ws;
  float* wT     = ws_f;                      // 65536
  float* Wall   = wT + 65536;                // 1492992
  float* Ball   = Wall + 1492992;            // 648 (pad 1024)
  float* q_hwc  = Ball + 1024;               // 4718592
  float* q_chw  = q_hwc + (size_t)BB * HW * CC;   // 4718592
  float* s_ln   = q_chw + (size_t)BB * HW * CC;   // 13824
  float* pooled = s_ln + 13824;              // 1536
  float* offbuf = pooled + 1536;             // 3*B*144*HW = 7962624
  float* mskbuf = offbuf + (size_t)3 * BB * 144 * HW;  // 3981312
  float* sim    = mskbuf + (size_t)3 * BB * 72 * HW;   // 442368

  k_transpose_w<<<dim3(256), dim3(256), 0, stream>>>(in_w, wT);
  k_packw<<<dim3((648 * 2304 + 255) / 256), dim3(256), 0, stream>>>(
      ow1, ob1, mw1, mb1, ow2, ob2, mw2, mb2, ow4, ob4, mw4, mb4, Wall, Ball);
  k_conv1_ln_q<<<dim3(576), dim3(256), 0, stream>>>(querys, wT, in_b, ln_g, ln_b, q_hwc);
  k_tr<<<dim3(288, 8, BB), dim3(32, 8), 0, stream>>>(q_hwc, q_chw);
  k_conv1_ln_s<<<dim3(6), dim3(256), 0, stream>>>(sup, wT, in_b, ln_g, ln_b, s_ln, pooled);
  k_conv3<<<dim3(96, 11, BB), dim3(256), 0, stream>>>(q_chw, Wall, Ball, offbuf, mskbuf);
  k_softmax<<<dim3(216), dim3(256), 0, stream>>>(mskbuf);
  k_sim0<<<dim3(12, 96, BB), dim3(256), 0, stream>>>(q_hwc, pooled, sim);
  k_deform<<<dim3(12, 96, 6), dim3(256), 0, stream>>>(q_hwc, offbuf, mskbuf, s_ln, sim);
  k_outconv<<<dim3(36, 256, BB), dim3(256), 0, stream>>>(sim, out_w, out_b, out);
}

// Round 4
// 956.170 us; speedup vs baseline: 2.0036x; 2.0036x over previous
//
#include <hip/hip_runtime.h>
#include <hip/hip_bf16.h>
#include <math.h>

#define HH 96
#define WWID 96
#define HW 9216
#define CC 256
#define BB 2
#define PROW 104
#define PCOL 128
#define PPX (PROW * PCOL)   // 13312

typedef float f32x4 __attribute__((ext_vector_type(4)));
typedef _Float16 f16x8 __attribute__((ext_vector_type(8)));

// in_w [C][C] -> wT [k][c]
__global__ void k_transpose_w(const float* __restrict__ in_w, float* __restrict__ wT) {
  int k = blockIdx.x, c = threadIdx.x;
  wT[k * CC + c] = in_w[c * CC + k];
}

// pack conv3x3 weights -> Whf [3 d][256 co][2304 k], k = j*256+ci, fp16; bias Ball[3*256]
__global__ void k_packw(const float* __restrict__ ow1, const float* __restrict__ ob1,
                        const float* __restrict__ mw1, const float* __restrict__ mb1,
                        const float* __restrict__ ow2, const float* __restrict__ ob2,
                        const float* __restrict__ mw2, const float* __restrict__ mb2,
                        const float* __restrict__ ow4, const float* __restrict__ ob4,
                        const float* __restrict__ mw4, const float* __restrict__ mb4,
                        _Float16* __restrict__ Whf, float* __restrict__ Ball) {
  int idx = blockIdx.x * 256 + threadIdx.x;
  if (idx >= 3 * 256 * 2304) return;
  int d = idx / (256 * 2304);
  int rem = idx - d * 256 * 2304;
  int co = rem / 2304;
  int k = rem - co * 2304;
  int j = k >> 8, ci = k & 255;
  const float* ow = d == 0 ? ow1 : (d == 1 ? ow2 : ow4);
  const float* mw = d == 0 ? mw1 : (d == 1 ? mw2 : mw4);
  float v = 0.f;
  if (co < 144) v = ow[co * 2304 + ci * 9 + j];
  else if (co < 216) v = mw[(co - 144) * 2304 + ci * 9 + j];
  Whf[idx] = (_Float16)v;
  if (idx < 768) {
    int dd = idx >> 8, cc = idx & 255;
    const float* obv = dd == 0 ? ob1 : (dd == 1 ? ob2 : ob4);
    const float* mbv = dd == 0 ? mb1 : (dd == 1 ? mb2 : mb4);
    float bv = 0.f;
    if (cc < 144) bv = obv[cc];
    else if (cc < 216) bv = mbv[cc - 144];
    Ball[idx] = bv;
  }
}

// conv1x1 + LayerNorm over channels for the query. Output NHWC q_hwc[b][hw][c].
__global__ void k_conv1_ln_q(const float* __restrict__ qin, const float* __restrict__ wT,
                             const float* __restrict__ in_b, const float* __restrict__ ln_g,
                             const float* __restrict__ ln_b, float* __restrict__ q_hwc) {
  int bx = blockIdx.x;
  int b = bx / 288;
  int hw0 = (bx % 288) * 32;
  int t = threadIdx.x;
  int lane = t & 63;
  int wv_id = t >> 6;
  __shared__ float xs[32 * 257];
  const float* qb = qin + (size_t)b * CC * HW;
  #pragma unroll
  for (int i = 0; i < 32; ++i) {
    int idx = t + i * 256;
    int p = idx & 31;
    int k = idx >> 5;
    xs[p * 257 + k] = qb[k * HW + hw0 + p];
  }
  __syncthreads();
  float acc[8][4];
  #pragma unroll
  for (int p = 0; p < 8; ++p) { acc[p][0]=0.f; acc[p][1]=0.f; acc[p][2]=0.f; acc[p][3]=0.f; }
  const float4* wT4 = (const float4*)wT;
  int p0 = wv_id * 8;
  for (int k = 0; k < 256; ++k) {
    float4 wv = wT4[k * 64 + lane];
    #pragma unroll
    for (int p = 0; p < 8; ++p) {
      float xv = xs[(p0 + p) * 257 + k];
      acc[p][0] += wv.x * xv; acc[p][1] += wv.y * xv;
      acc[p][2] += wv.z * xv; acc[p][3] += wv.w * xv;
    }
  }
  float4 bb = ((const float4*)in_b)[lane];
  float4 g4 = ((const float4*)ln_g)[lane];
  float4 b4 = ((const float4*)ln_b)[lane];
  #pragma unroll
  for (int p = 0; p < 8; ++p) {
    float y0 = acc[p][0] + bb.x, y1 = acc[p][1] + bb.y;
    float y2 = acc[p][2] + bb.z, y3 = acc[p][3] + bb.w;
    float s1 = y0 + y1 + y2 + y3;
    float s2 = y0*y0 + y1*y1 + y2*y2 + y3*y3;
    #pragma unroll
    for (int off = 32; off; off >>= 1) { s1 += __shfl_xor(s1, off); s2 += __shfl_xor(s2, off); }
    float mu = s1 * (1.f / 256.f);
    float rstd = rsqrtf(s2 * (1.f / 256.f) - mu * mu + 1e-5f);
    float4 o;
    o.x = (y0 - mu) * rstd * g4.x + b4.x;
    o.y = (y1 - mu) * rstd * g4.y + b4.y;
    o.z = (y2 - mu) * rstd * g4.z + b4.z;
    o.w = (y3 - mu) * rstd * g4.w + b4.w;
    ((float4*)q_hwc)[((size_t)b * HW + hw0 + p0 + p) * 64 + lane] = o;
  }
}

// build zero-padded fp16 NHWC grid: qpad [B][104*128 ppx][256 ch]
__global__ void k_pad(const float* __restrict__ q_hwc, _Float16* __restrict__ qpad) {
  int gid = blockIdx.x * 256 + threadIdx.x;   // each thread: 8 channels of one ppx
  if (gid >= BB * PPX * 32) return;
  int c0 = (gid & 31) * 8;
  int p = gid >> 5;           // b*PPX + ppx
  int b = p / PPX;
  int ppx = p - b * PPX;
  int rowp = ppx >> 7, colp = ppx & 127;
  struct alignas(16) h8 { _Float16 h[8]; };
  h8 o;
  if (rowp >= 4 && rowp < 100 && colp >= 4 && colp < 100) {
    const float* src = q_hwc + ((size_t)b * HW + (rowp - 4) * 96 + (colp - 4)) * CC + c0;
    float4 s1 = ((const float4*)src)[0];
    float4 s2 = ((const float4*)src)[1];
    o.h[0] = (_Float16)s1.x; o.h[1] = (_Float16)s1.y;
    o.h[2] = (_Float16)s1.z; o.h[3] = (_Float16)s1.w;
    o.h[4] = (_Float16)s2.x; o.h[5] = (_Float16)s2.y;
    o.h[6] = (_Float16)s2.z; o.h[7] = (_Float16)s2.w;
  } else {
    #pragma unroll
    for (int i = 0; i < 8; ++i) o.h[i] = (_Float16)0.f;
  }
  *(h8*)(qpad + (size_t)p * CC + c0) = o;
}

// supports: conv1x1 + LN per (b,e) image of 9 positions; also pooled max.
__global__ void k_conv1_ln_s(const float* __restrict__ sup, const float* __restrict__ wT,
                             const float* __restrict__ in_b, const float* __restrict__ ln_g,
                             const float* __restrict__ ln_b, float* __restrict__ s_ln,
                             float* __restrict__ pooled) {
  int img = blockIdx.x;  // b*3+e
  int t = threadIdx.x;
  __shared__ float xs[2304];
  __shared__ float red1[256], red2[256];
  #pragma unroll
  for (int p = 0; p < 9; ++p) xs[t * 9 + p] = sup[(size_t)img * 2304 + t * 9 + p];
  __syncthreads();
  float acc[9];
  #pragma unroll
  for (int p = 0; p < 9; ++p) acc[p] = 0.f;
  for (int k = 0; k < 256; ++k) {
    float wv = wT[k * CC + t];
    #pragma unroll
    for (int p = 0; p < 9; ++p) acc[p] += wv * xs[k * 9 + p];
  }
  float bias = in_b[t];
  #pragma unroll
  for (int p = 0; p < 9; ++p) acc[p] += bias;
  float g = ln_g[t], be = ln_b[t];
  float vals[9];
  #pragma unroll
  for (int p = 0; p < 9; ++p) {
    red1[t] = acc[p]; red2[t] = acc[p] * acc[p];
    __syncthreads();
    for (int s = 128; s > 0; s >>= 1) {
      if (t < s) { red1[t] += red1[t + s]; red2[t] += red2[t + s]; }
      __syncthreads();
    }
    float mu = red1[0] * (1.f / 256.f);
    float var = red2[0] * (1.f / 256.f) - mu * mu;
    float rstd = rsqrtf(var + 1e-5f);
    vals[p] = (acc[p] - mu) * rstd * g + be;
    __syncthreads();
  }
  #pragma unroll
  for (int p = 0; p < 9; ++p) s_ln[(size_t)img * 2304 + t * 9 + p] = vals[p];
  float mx = vals[0];
  #pragma unroll
  for (int p = 1; p < 9; ++p) mx = fmaxf(mx, vals[p]);
  int b = img / 3, e = img % 3;
  pooled[((size_t)b * 6 + e * 2 + (t >> 7)) * 128 + (t & 127)] = mx;
}

// fp16 MFMA implicit-GEMM conv3x3.
// NOTE: the reference's offset/mask convs are ALL dilation-1 3x3 convs (pad=1);
// the "dilation" d only affects deform_conv's sampling grid, NOT these convs.
// C[co 0..215][px 0..9215] = W_d[co][k] * B[k][px], k = j*256+ci,
// B[k][px] = qpad[b][ppx(px) + off(j)][ci]  (same B for all d).
// grid: x = 72 N-tiles(128 px), y = 2 M-tiles(128 co), z = d*2+b.
__global__ void __launch_bounds__(256) k_conv3_mfma(
    const _Float16* __restrict__ qpad, const _Float16* __restrict__ Whf,
    const float* __restrict__ Ball, float* __restrict__ offbuf, float* __restrict__ mskbuf) {
  int nb = blockIdx.x;
  int mb = blockIdx.y;
  int z = blockIdx.z;
  int d = z >> 1, b = z & 1;
  int t = threadIdx.x;
  int lane = t & 63, wv = t >> 6;
  int wm = wv >> 1, wn = wv & 1;
  int quad = lane >> 4, l15 = lane & 15;

  __shared__ _Float16 __attribute__((aligned(16))) As[128 * 40];
  __shared__ _Float16 __attribute__((aligned(16))) Bs[128 * 40];

  // staging mapping: thread t -> rows (t>>2, t>>2 + 64), k-quad (t&3)
  int srow = t >> 2;
  int qc = t & 3;
  const _Float16* Wd = Whf + (size_t)d * 256 * 2304;
  size_t aG1 = (size_t)(mb * 128 + srow) * 2304 + qc * 8;
  size_t aG2 = (size_t)(mb * 128 + srow + 64) * 2304 + qc * 8;
  int px1 = nb * 128 + srow, px2 = px1 + 64;
  int h1 = px1 / 96, w1 = px1 - h1 * 96;
  int h2 = px2 / 96, w2 = px2 - h2 * 96;
  int ppx1 = (h1 + 4) * PCOL + w1 + 4;
  int ppx2 = (h2 + 4) * PCOL + w2 + 4;
  const _Float16* qb = qpad + (size_t)b * PPX * CC;

  int awr1 = srow * 40 + qc * 8;
  int awr2 = (srow + 64) * 40 + qc * 8;

  int aOff[4], bOff[4];
  #pragma unroll
  for (int i = 0; i < 4; ++i) {
    aOff[i] = (wm * 64 + i * 16 + l15) * 40 + quad * 8;
    bOff[i] = (wn * 64 + i * 16 + l15) * 40 + quad * 8;
  }

  f32x4 acc[16];
  #pragma unroll
  for (int i = 0; i < 16; ++i) acc[i] = (f32x4){0.f, 0.f, 0.f, 0.f};

  int4 ra1, ra2, rb1, rb2;
  // prefetch iter 0  (jj=0 -> tap (-1,-1), dilation-1 ALWAYS)
  {
    ra1 = *(const int4*)(Wd + aG1);
    ra2 = *(const int4*)(Wd + aG2);
    int offp = -PCOL - 1;
    rb1 = *(const int4*)(qb + (size_t)(ppx1 + offp) * CC + qc * 8);
    rb2 = *(const int4*)(qb + (size_t)(ppx2 + offp) * CC + qc * 8);
  }

  for (int iter = 0; iter < 72; ++iter) {
    __syncthreads();
    *(int4*)(As + awr1) = ra1;
    *(int4*)(As + awr2) = ra2;
    *(int4*)(Bs + awr1) = rb1;
    *(int4*)(Bs + awr2) = rb2;
    __syncthreads();
    if (iter < 71) {
      int it = iter + 1;
      int kbase = it * 32;
      int ci0 = (it & 7) * 32;
      int jj = it >> 3;
      int offp = (jj / 3 - 1) * PCOL + (jj % 3 - 1);   // dilation-1 taps for ALL d
      ra1 = *(const int4*)(Wd + aG1 + kbase);
      ra2 = *(const int4*)(Wd + aG2 + kbase);
      rb1 = *(const int4*)(qb + (size_t)(ppx1 + offp) * CC + ci0 + qc * 8);
      rb2 = *(const int4*)(qb + (size_t)(ppx2 + offp) * CC + ci0 + qc * 8);
    }
    f16x8 af[4], bf[4];
    #pragma unroll
    for (int i = 0; i < 4; ++i) {
      af[i] = *(const f16x8*)(As + aOff[i]);
      bf[i] = *(const f16x8*)(Bs + bOff[i]);
    }
    #pragma unroll
    for (int mi = 0; mi < 4; ++mi)
      #pragma unroll
      for (int ni = 0; ni < 4; ++ni)
        acc[mi * 4 + ni] = __builtin_amdgcn_mfma_f32_16x16x32_f16(af[mi], bf[ni], acc[mi * 4 + ni], 0, 0, 0);
  }

  // epilogue: C row = co = mb*128 + wm*64 + mi*16 + quad*4 + reg ; col = px
  #pragma unroll
  for (int mi = 0; mi < 4; ++mi) {
    int coB = mb * 128 + wm * 64 + mi * 16 + quad * 4;
    #pragma unroll
    for (int ni = 0; ni < 4; ++ni) {
      int px = nb * 128 + wn * 64 + ni * 16 + l15;
      f32x4 v = acc[mi * 4 + ni];
      #pragma unroll
      for (int r = 0; r < 4; ++r) {
        int c2 = coB + r;
        if (c2 < 216) {
          float val = v[r] + Ball[d * 256 + c2];
          if (c2 < 144) offbuf[((size_t)(d * BB + b) * 144 + c2) * HW + px] = val;
          else mskbuf[((size_t)(d * BB + b) * 72 + (c2 - 144)) * HW + px] = val;
        }
      }
    }
  }
}

// softmax over 72 mask channels per pixel, in place
__global__ void k_softmax(float* __restrict__ msk) {
  int gid = blockIdx.x * 256 + threadIdx.x;
  int img = gid / HW, hw = gid % HW;
  float* p = msk + (size_t)img * 72 * HW + hw;
  float mx = -1e30f;
  for (int r = 0; r < 72; ++r) mx = fmaxf(mx, p[r * HW]);
  float s = 0.f;
  for (int r = 0; r < 72; ++r) s += __expf(p[r * HW] - mx);
  float rinv = 1.f / s;
  for (int r = 0; r < 72; ++r) p[r * HW] = __expf(p[r * HW] - mx) * rinv;
}

// sim0 branch: grouped 1x1 with pooled weights. block = 8 px x 32 lanes.
__global__ void k_sim0(const float* __restrict__ qt, const float* __restrict__ pooled,
                       float* __restrict__ sim) {
  int b = blockIdx.z, h = blockIdx.y, seg = blockIdx.x;
  int t = threadIdx.x;
  int pxl = t >> 5, lane = t & 31;
  int wcol = seg * 8 + pxl;
  int hw = h * WWID + wcol;
  __shared__ float plds[768];
  for (int i = t; i < 768; i += 256) plds[i] = pooled[(size_t)b * 768 + i];
  __syncthreads();
  const float* qtb = qt + (size_t)b * HW * CC;
  float acc[6] = {0.f, 0.f, 0.f, 0.f, 0.f, 0.f};
  #pragma unroll
  for (int m = 0; m < 8; ++m) {
    int cfull = m * 32 + lane;
    float qv = qtb[(size_t)hw * CC + cfull];
    if (m < 4) {
      int cp = cfull;
      acc[0] += plds[0 * 128 + cp] * qv;
      acc[1] += plds[1 * 128 + cp] * qv;
      acc[2] += plds[2 * 128 + cp] * qv;
    } else {
      int cp = cfull - 128;
      acc[3] += plds[3 * 128 + cp] * qv;
      acc[4] += plds[4 * 128 + cp] * qv;
      acc[5] += plds[5 * 128 + cp] * qv;
    }
  }
  #pragma unroll
  for (int r = 0; r < 6; ++r) {
    float v = acc[r];
    #pragma unroll
    for (int off = 16; off; off >>= 1) v += __shfl_down(v, off, 32);
    if (lane == 0) sim[((size_t)b * 24 + r) * HW + hw] = v;
  }
}

// deformable conv: block = 8 px x 32 lanes, one (b, dilation) per blockIdx.z
__global__ void k_deform(const float* __restrict__ qt, const float* __restrict__ offbuf,
                         const float* __restrict__ mskbuf, const float* __restrict__ s_ln,
                         float* __restrict__ sim) {
  int z = blockIdx.z;
  int d_idx = z >> 1, b = z & 1;
  int dil = 1 << d_idx;
  int h = blockIdx.y, seg = blockIdx.x;
  int t = threadIdx.x;
  int pxl = t >> 5, lane = t & 31;
  int wcol = seg * 8 + pxl;
  int hw = h * WWID + wcol;
  __shared__ float wlds[6912];
  for (int i = t; i < 6912; i += 256) wlds[i] = s_ln[(size_t)b * 6912 + i];
  __syncthreads();
  const float* ob = offbuf + (size_t)z * 144 * HW + hw;
  const float* mb = mskbuf + (size_t)z * 72 * HW + hw;
  const float* qtb = qt + (size_t)b * HW * CC;
  float acc[6] = {0.f, 0.f, 0.f, 0.f, 0.f, 0.f};
  for (int og = 0; og < 8; ++og) {
    int cfull = og * 32 + lane;
    #pragma unroll
    for (int k = 0; k < 9; ++k) {
      float dy = ob[((og * 9 + k) * 2 + 0) * HW];
      float dx = ob[((og * 9 + k) * 2 + 1) * HW];
      float mval = mb[(og * 9 + k) * HW];
      float py = (float)(h + (k / 3) * dil - dil) + dy;
      float px = (float)(wcol + (k % 3) * dil - dil) + dx;
      float y0f = floorf(py), x0f = floorf(px);
      int y0 = (int)y0f, x0 = (int)x0f;
      float wy = py - y0f, wx = px - x0f;
      float w00 = (1.f - wy) * (1.f - wx), w01 = (1.f - wy) * wx;
      float w10 = wy * (1.f - wx), w11 = wy * wx;
      float s = 0.f;
      if ((unsigned)y0 < 96u && (unsigned)x0 < 96u)
        s += w00 * qtb[(size_t)(y0 * 96 + x0) * CC + cfull];
      if ((unsigned)y0 < 96u && (unsigned)(x0 + 1) < 96u)
        s += w01 * qtb[(size_t)(y0 * 96 + x0 + 1) * CC + cfull];
      if ((unsigned)(y0 + 1) < 96u && (unsigned)x0 < 96u)
        s += w10 * qtb[(size_t)((y0 + 1) * 96 + x0) * CC + cfull];
      if ((unsigned)(y0 + 1) < 96u && (unsigned)(x0 + 1) < 96u)
        s += w11 * qtb[(size_t)((y0 + 1) * 96 + x0 + 1) * CC + cfull];
      s *= mval;
      if (og < 4) {
        int cp = cfull;
        acc[0] += wlds[(0 * 256 + 0 * 128 + cp) * 9 + k] * s;
        acc[1] += wlds[(0 * 256 + 1 * 128 + cp) * 9 + k] * s;
        acc[2] += wlds[(1 * 256 + 0 * 128 + cp) * 9 + k] * s;
      } else {
        int cp = cfull - 128;
        acc[3] += wlds[(1 * 256 + 1 * 128 + cp) * 9 + k] * s;
        acc[4] += wlds[(2 * 256 + 0 * 128 + cp) * 9 + k] * s;
        acc[5] += wlds[(2 * 256 + 1 * 128 + cp) * 9 + k] * s;
      }
    }
  }
  #pragma unroll
  for (int r = 0; r < 6; ++r) {
    float v = acc[r];
    #pragma unroll
    for (int off = 16; off; off >>= 1) v += __shfl_down(v, off, 32);
    if (lane == 0) sim[((size_t)b * 24 + 6 + 6 * d_idx + r) * HW + hw] = v;
  }
}

// out 1x1 conv: sim [B][24][HW] x out_w [256][24] -> out [B][256][HW]
__global__ void k_outconv(const float* __restrict__ sim, const float* __restrict__ out_w,
                          const float* __restrict__ out_b, float* __restrict__ out) {
  int hw = blockIdx.x * 256 + threadIdx.x;
  int co = blockIdx.y, b = blockIdx.z;
  const float* simb = sim + (size_t)b * 24 * HW;
  float a = out_b[co];
  #pragma unroll
  for (int r = 0; r < 24; ++r) a += out_w[co * 24 + r] * simb[(size_t)r * HW + hw];
  out[((size_t)b * CC + co) * HW + hw] = a;
}

extern "C" void kernel_launch(void* const* d_in, const int* in_sizes, int n_in,
                              void* d_out, int out_size, void* d_ws, size_t ws_size,
                              hipStream_t stream) {
  const float* querys = (const float*)d_in[0];
  const float* sup    = (const float*)d_in[1];
  const float* in_w   = (const float*)d_in[2];
  const float* in_b   = (const float*)d_in[3];
  const float* ln_g   = (const float*)d_in[4];
  const float* ln_b   = (const float*)d_in[5];
  const float* out_w  = (const float*)d_in[6];
  const float* out_b  = (const float*)d_in[7];
  const float* ow1 = (const float*)d_in[8];
  const float* ob1 = (const float*)d_in[9];
  const float* mw1 = (const float*)d_in[10];
  const float* mb1 = (const float*)d_in[11];
  const float* ow2 = (const float*)d_in[12];
  const float* ob2 = (const float*)d_in[13];
  const float* mw2 = (const float*)d_in[14];
  const float* mb2 = (const float*)d_in[15];
  const float* ow4 = (const float*)d_in[16];
  const float* ob4 = (const float*)d_in[17];
  const float* mw4 = (const float*)d_in[18];
  const float* mb4 = (const float*)d_in[19];
  float* out = (float*)d_out;

  float* ws_f   = (float*)d_ws;
  float* wT     = ws_f;                              // 65536 floats
  _Float16* Whf = (_Float16*)(wT + 65536);           // 3*256*2304 fp16 = 884736 float slots
  float* Ball   = (float*)(Whf + 3 * 256 * 2304);    // 768 (pad 1024)
  float* q_hwc  = Ball + 1024;                       // 4718592
  _Float16* qpad = (_Float16*)(q_hwc + (size_t)BB * HW * CC);  // 2*13312*256 fp16
  float* s_ln   = (float*)(qpad + (size_t)BB * PPX * CC);  // 13824
  float* pooled = s_ln + 13824;                      // 1536
  float* offbuf = pooled + 1536;                     // 3*B*144*HW = 7962624
  float* mskbuf = offbuf + (size_t)3 * BB * 144 * HW;  // 3981312
  float* sim    = mskbuf + (size_t)3 * BB * 72 * HW;   // 442368

  k_transpose_w<<<dim3(256), dim3(256), 0, stream>>>(in_w, wT);
  k_packw<<<dim3((3 * 256 * 2304 + 255) / 256), dim3(256), 0, stream>>>(
      ow1, ob1, mw1, mb1, ow2, ob2, mw2, mb2, ow4, ob4, mw4, mb4, Whf, Ball);
  k_conv1_ln_q<<<dim3(576), dim3(256), 0, stream>>>(querys, wT, in_b, ln_g, ln_b, q_hwc);
  k_pad<<<dim3((BB * PPX * 32 + 255) / 256), dim3(256), 0, stream>>>(q_hwc, qpad);
  k_conv1_ln_s<<<dim3(6), dim3(256), 0, stream>>>(sup, wT, in_b, ln_g, ln_b, s_ln, pooled);
  k_conv3_mfma<<<dim3(72, 2, 6), dim3(256), 0, stream>>>(qpad, Whf, Ball, offbuf, mskbuf);
  k_softmax<<<dim3(216), dim3(256), 0, stream>>>(mskbuf);
  k_sim0<<<dim3(12, 96, BB), dim3(256), 0, stream>>>(q_hwc, pooled, sim);
  k_deform<<<dim3(12, 96, 6), dim3(256), 0, stream>>>(q_hwc, offbuf, mskbuf, s_ln, sim);
  k_outconv<<<dim3(36, 256, BB), dim3(256), 0, stream>>>(sim, out_w, out_b, out);
}